// Round 2
// baseline (356.972 us; speedup 1.0000x reference)
//
#include <hip/hip_runtime.h>
#include <hip/hip_bf16.h>
#include <hip/hip_fp16.h>

typedef unsigned short u16;
typedef __attribute__((ext_vector_type(8))) short short8;
typedef __attribute__((ext_vector_type(8))) u16 u16x8;
typedef __attribute__((ext_vector_type(4))) u16 u16x4;
typedef __attribute__((ext_vector_type(8))) _Float16 half8;
typedef __attribute__((ext_vector_type(4))) float f32x4;

#define NB 8
#define TQn 1024
#define TKn 4096
#define DINn 1024
#define DOUTn 256
#define NEGINF (-1e30f)

#define DEV static __device__ __forceinline__

DEV u16 f2bf(float x) {
    __hip_bfloat16 h = __float2bfloat16(x);
    return *reinterpret_cast<u16*>(&h);
}
DEV float bf2f(u16 u) {
    __hip_bfloat16 h;
    *reinterpret_cast<u16*>(&h) = u;
    return __bfloat162float(h);
}
DEV void split2(float x, u16& hi, u16& lo) {
    u16 h = f2bf(x);
    float hf = bf2f(h);
    hi = h;
    lo = f2bf(x - hf);
}
DEV void split4(const float4 v, u16x4& h, u16x4& l) {
    u16 h0, l0, h1, l1, h2, l2, h3, l3;
    split2(v.x, h0, l0);
    split2(v.y, h1, l1);
    split2(v.z, h2, l2);
    split2(v.w, h3, l3);
    h = (u16x4){h0, h1, h2, h3};
    l = (u16x4){l0, l1, l2, l3};
}

// ---------------------------------------------------------------------------
// Kernel 1: transpose+convert emb [B][TK][DOUT] fp32 -> embT [B][DOUT][TK] fp16
// ---------------------------------------------------------------------------
__global__ __launch_bounds__(256) void k_embT(const float* __restrict__ emb,
                                              _Float16* __restrict__ embT) {
    __shared__ float tile[64][65];
    const int b = blockIdx.z;
    const int k0 = blockIdx.x * 64;
    const int o0 = blockIdx.y * 64;
    const int t = threadIdx.x;
    const int c = t & 63;
    const int r0 = t >> 6;
#pragma unroll
    for (int i = 0; i < 16; i++) {
        int r = r0 + i * 4;  // k-local
        tile[c][r] = emb[((size_t)b * TKn + k0 + r) * DOUTn + o0 + c];
    }
    __syncthreads();
#pragma unroll
    for (int i = 0; i < 16; i++) {
        int r = r0 + i * 4;  // o-local
        embT[((size_t)b * DOUTn + o0 + r) * TKn + k0 + c] = (_Float16)tile[r][c];
    }
}

// ---------------------------------------------------------------------------
// Kernel 2: linear  decsmall = dec @ W^T + b, split into hi/lo bf16
// BM=128, BN=64, BK=32, 256 threads (4 waves, 2x2)
// ---------------------------------------------------------------------------
__global__ __launch_bounds__(256) void k_linear(const float* __restrict__ dec,
                                                const float* __restrict__ W,
                                                const float* __restrict__ bias,
                                                u16* __restrict__ ds_hi,
                                                u16* __restrict__ ds_lo) {
    __shared__ u16 sAh[128][40], sAl[128][40], sBh[64][40], sBl[64][40];
    const int t = threadIdx.x;
    const int m0 = blockIdx.x * 128;
    const int n0 = blockIdx.y * 64;
    const int w = t >> 6, lane = t & 63;
    const int wr = w >> 1, wc = w & 1;
    const int lr = lane & 15, kg8 = (lane >> 4) * 8;

    f32x4 acc[4][2];
#pragma unroll
    for (int m = 0; m < 4; m++)
#pragma unroll
        for (int n = 0; n < 2; n++) acc[m][n] = (f32x4){0.f, 0.f, 0.f, 0.f};

    for (int k0 = 0; k0 < DINn; k0 += 32) {
        __syncthreads();
        // stage A (dec) 128x32 fp32 -> hi/lo
#pragma unroll
        for (int i = 0; i < 4; i++) {
            int f = i * 256 + t;
            int row = f >> 3, c4 = (f & 7) * 4;
            const float4 v = *reinterpret_cast<const float4*>(
                dec + (size_t)(m0 + row) * DINn + k0 + c4);
            u16x4 h, l;
            split4(v, h, l);
            *reinterpret_cast<u16x4*>(&sAh[row][c4]) = h;
            *reinterpret_cast<u16x4*>(&sAl[row][c4]) = l;
        }
        // stage B (W) 64x32 fp32 -> hi/lo
#pragma unroll
        for (int i = 0; i < 2; i++) {
            int f = i * 256 + t;
            int row = f >> 3, c4 = (f & 7) * 4;
            const float4 v = *reinterpret_cast<const float4*>(
                W + (size_t)(n0 + row) * DINn + k0 + c4);
            u16x4 h, l;
            split4(v, h, l);
            *reinterpret_cast<u16x4*>(&sBh[row][c4]) = h;
            *reinterpret_cast<u16x4*>(&sBl[row][c4]) = l;
        }
        __syncthreads();
        short8 ah[4], al[4], bh[2], bl[2];
#pragma unroll
        for (int m = 0; m < 4; m++) {
            int row = wr * 64 + m * 16 + lr;
            ah[m] = *reinterpret_cast<const short8*>(&sAh[row][kg8]);
            al[m] = *reinterpret_cast<const short8*>(&sAl[row][kg8]);
        }
#pragma unroll
        for (int n = 0; n < 2; n++) {
            int row = wc * 32 + n * 16 + lr;
            bh[n] = *reinterpret_cast<const short8*>(&sBh[row][kg8]);
            bl[n] = *reinterpret_cast<const short8*>(&sBl[row][kg8]);
        }
#pragma unroll
        for (int m = 0; m < 4; m++)
#pragma unroll
            for (int n = 0; n < 2; n++) {
                acc[m][n] = __builtin_amdgcn_mfma_f32_16x16x32_bf16(ah[m], bh[n], acc[m][n], 0, 0, 0);
                acc[m][n] = __builtin_amdgcn_mfma_f32_16x16x32_bf16(ah[m], bl[n], acc[m][n], 0, 0, 0);
                acc[m][n] = __builtin_amdgcn_mfma_f32_16x16x32_bf16(al[m], bh[n], acc[m][n], 0, 0, 0);
            }
    }
    // epilogue: + bias, split-write
#pragma unroll
    for (int m = 0; m < 4; m++) {
#pragma unroll
        for (int n = 0; n < 2; n++) {
            int colg = n0 + wc * 32 + n * 16 + lr;
            float bv = bias[colg];
#pragma unroll
            for (int r = 0; r < 4; r++) {
                int rowg = m0 + wr * 64 + m * 16 + (lane >> 4) * 4 + r;
                float v = acc[m][n][r] + bv;
                u16 h, l;
                split2(v, h, l);
                ds_hi[(size_t)rowg * DOUTn + colg] = h;
                ds_lo[(size_t)rowg * DOUTn + colg] = l;
            }
        }
    }
}

// ---------------------------------------------------------------------------
// Kernel 3: scores = decsmall @ emb^T (split 3-MFMA), mask, write fp32 scores
// BM=128, BN=128, BK=32, 256 threads (4 waves, 2x2), K=DOUT=256
// ---------------------------------------------------------------------------
__global__ __launch_bounds__(256) void k_scores(const u16* __restrict__ ds_hi,
                                                const u16* __restrict__ ds_lo,
                                                const float* __restrict__ emb,
                                                const int* __restrict__ emask,
                                                float* __restrict__ attn) {
    __shared__ u16 sAh[128][40], sAl[128][40], sBh[128][40], sBl[128][40];
    const int t = threadIdx.x;
    const int q0 = blockIdx.x * 128;
    const int kb0 = blockIdx.y * 128;
    const int b = blockIdx.z;
    const int w = t >> 6, lane = t & 63;
    const int wr = w >> 1, wc = w & 1;
    const int lr = lane & 15, kg8 = (lane >> 4) * 8;

    f32x4 acc[4][4];
#pragma unroll
    for (int m = 0; m < 4; m++)
#pragma unroll
        for (int n = 0; n < 4; n++) acc[m][n] = (f32x4){0.f, 0.f, 0.f, 0.f};

    for (int o0 = 0; o0 < DOUTn; o0 += 32) {
        __syncthreads();
        // stage A (decsmall hi/lo bf16) 128x32
#pragma unroll
        for (int i = 0; i < 2; i++) {
            int f8 = i * 256 + t;
            int row = f8 >> 2, c8 = (f8 & 3) * 8;
            size_t src = (size_t)(b * TQn + q0 + row) * DOUTn + o0 + c8;
            *reinterpret_cast<u16x8*>(&sAh[row][c8]) =
                *reinterpret_cast<const u16x8*>(ds_hi + src);
            *reinterpret_cast<u16x8*>(&sAl[row][c8]) =
                *reinterpret_cast<const u16x8*>(ds_lo + src);
        }
        // stage B (emb fp32) 128x32 -> hi/lo
#pragma unroll
        for (int i = 0; i < 4; i++) {
            int f = i * 256 + t;
            int row = f >> 3, c4 = (f & 7) * 4;
            const float4 v = *reinterpret_cast<const float4*>(
                emb + (size_t)(b * TKn + kb0 + row) * DOUTn + o0 + c4);
            u16x4 h, l;
            split4(v, h, l);
            *reinterpret_cast<u16x4*>(&sBh[row][c4]) = h;
            *reinterpret_cast<u16x4*>(&sBl[row][c4]) = l;
        }
        __syncthreads();
        short8 ah[4], al[4], bh[4], bl[4];
#pragma unroll
        for (int m = 0; m < 4; m++) {
            int row = wr * 64 + m * 16 + lr;
            ah[m] = *reinterpret_cast<const short8*>(&sAh[row][kg8]);
            al[m] = *reinterpret_cast<const short8*>(&sAl[row][kg8]);
        }
#pragma unroll
        for (int n = 0; n < 4; n++) {
            int row = wc * 64 + n * 16 + lr;
            bh[n] = *reinterpret_cast<const short8*>(&sBh[row][kg8]);
            bl[n] = *reinterpret_cast<const short8*>(&sBl[row][kg8]);
        }
#pragma unroll
        for (int m = 0; m < 4; m++)
#pragma unroll
            for (int n = 0; n < 4; n++) {
                acc[m][n] = __builtin_amdgcn_mfma_f32_16x16x32_bf16(ah[m], bh[n], acc[m][n], 0, 0, 0);
                acc[m][n] = __builtin_amdgcn_mfma_f32_16x16x32_bf16(ah[m], bl[n], acc[m][n], 0, 0, 0);
                acc[m][n] = __builtin_amdgcn_mfma_f32_16x16x32_bf16(al[m], bh[n], acc[m][n], 0, 0, 0);
            }
    }
    // epilogue: mask + write scores
    const int* em = emask + (size_t)b * TKn;
    float* out = attn + ((size_t)(b * TQn + q0)) * TKn + kb0;
#pragma unroll
    for (int n = 0; n < 4; n++) {
        int colL = wc * 64 + n * 16 + lr;
        int mk = em[kb0 + colL];
#pragma unroll
        for (int m = 0; m < 4; m++) {
#pragma unroll
            for (int r = 0; r < 4; r++) {
                int rowL = wr * 64 + m * 16 + (lane >> 4) * 4 + r;
                float v = (mk == 0) ? NEGINF : acc[m][n][r];
                out[(size_t)rowL * TKn + colL] = v;
            }
        }
    }
}

// ---------------------------------------------------------------------------
// Kernel 4: row stats: max, then write exp(s-m) in place + inv_sum
// 512 blocks x 256 thr; each wave handles 4 rows
// ---------------------------------------------------------------------------
__global__ __launch_bounds__(256) void k_stats(float* __restrict__ attn,
                                               float* __restrict__ inv_sum) {
    const int t = threadIdx.x, w = t >> 6, lane = t & 63;
    for (int rr = 0; rr < 4; rr++) {
        const int rowg = blockIdx.x * 16 + w * 4 + rr;
        float* base = attn + (size_t)rowg * TKn;
        float m = -INFINITY;
        for (int i = 0; i < 16; i++) {
            f32x4 v = *reinterpret_cast<const f32x4*>(base + i * 256 + lane * 4);
            m = fmaxf(m, fmaxf(fmaxf(v[0], v[1]), fmaxf(v[2], v[3])));
        }
#pragma unroll
        for (int off = 32; off >= 1; off >>= 1) m = fmaxf(m, __shfl_xor(m, off));
        float s = 0.f;
        for (int i = 0; i < 16; i++) {
            f32x4 v = *reinterpret_cast<const f32x4*>(base + i * 256 + lane * 4);
            f32x4 e;
            e[0] = __expf(v[0] - m);
            e[1] = __expf(v[1] - m);
            e[2] = __expf(v[2] - m);
            e[3] = __expf(v[3] - m);
            *reinterpret_cast<f32x4*>(base + i * 256 + lane * 4) = e;
            s += e[0] + e[1] + e[2] + e[3];
        }
#pragma unroll
        for (int off = 32; off >= 1; off >>= 1) s += __shfl_xor(s, off);
        if (lane == 0) inv_sum[rowg] = 1.0f / s;
    }
}

// ---------------------------------------------------------------------------
// Kernel 5: scale p in place (final attn) + PV partial via fp16 MFMA
// grid (TQ/64, 4 k-chunks, B); 256 thr; wave w owns rows w*16+lr; no LDS
// ---------------------------------------------------------------------------
__global__ __launch_bounds__(256) void k_pv(float* __restrict__ attn,
                                            const _Float16* __restrict__ embT,
                                            const float* __restrict__ inv_sum,
                                            float* __restrict__ partial) {
    const int t = threadIdx.x, w = t >> 6, lane = t & 63;
    const int lr = lane & 15, g = lane >> 4, kg8 = g * 8;
    const int q64 = blockIdx.x * 64;
    const int kc = blockIdx.y;
    const int b = blockIdx.z;
    const int rowL = w * 16 + lr;
    const size_t growBase = (size_t)b * TQn + q64;

    float* prow = attn + (growBase + rowL) * TKn + kc * 1024 + kg8;
    const float inv = inv_sum[growBase + rowL];
    const _Float16* eb = embT + (size_t)b * DOUTn * TKn + kc * 1024 + kg8;

    f32x4 acc[16];
#pragma unroll
    for (int n = 0; n < 16; n++) acc[n] = (f32x4){0.f, 0.f, 0.f, 0.f};

    for (int kt = 0; kt < 32; kt++) {
        f32x4 v0 = *reinterpret_cast<const f32x4*>(prow + kt * 32);
        f32x4 v1 = *reinterpret_cast<const f32x4*>(prow + kt * 32 + 4);
        v0 = v0 * inv;
        v1 = v1 * inv;
        *reinterpret_cast<f32x4*>(prow + kt * 32) = v0;
        *reinterpret_cast<f32x4*>(prow + kt * 32 + 4) = v1;
        half8 pa;
        pa[0] = (_Float16)v0[0];
        pa[1] = (_Float16)v0[1];
        pa[2] = (_Float16)v0[2];
        pa[3] = (_Float16)v0[3];
        pa[4] = (_Float16)v1[0];
        pa[5] = (_Float16)v1[1];
        pa[6] = (_Float16)v1[2];
        pa[7] = (_Float16)v1[3];
#pragma unroll
        for (int n = 0; n < 16; n++) {
            half8 bf = *reinterpret_cast<const half8*>(eb + (size_t)(n * 16 + lr) * TKn + kt * 32);
            acc[n] = __builtin_amdgcn_mfma_f32_16x16x32_f16(pa, bf, acc[n], 0, 0, 0);
        }
    }
#pragma unroll
    for (int n = 0; n < 16; n++) {
        int col = n * 16 + lr;
#pragma unroll
        for (int r = 0; r < 4; r++) {
            size_t grow = growBase + w * 16 + g * 4 + r;
            partial[((size_t)kc * (NB * TQn) + grow) * DOUTn + col] = acc[n][r];
        }
    }
}

// ---------------------------------------------------------------------------
// Kernel 6: out = sum of 4 partials
// ---------------------------------------------------------------------------
__global__ __launch_bounds__(256) void k_reduce(const float* __restrict__ partial,
                                                float* __restrict__ out) {
    const size_t stride = (size_t)NB * TQn * DOUTn;
    size_t i = ((size_t)blockIdx.x * 256 + threadIdx.x) * 4;
    f32x4 a0 = *reinterpret_cast<const f32x4*>(partial + i);
    f32x4 a1 = *reinterpret_cast<const f32x4*>(partial + stride + i);
    f32x4 a2 = *reinterpret_cast<const f32x4*>(partial + 2 * stride + i);
    f32x4 a3 = *reinterpret_cast<const f32x4*>(partial + 3 * stride + i);
    f32x4 s = (a0 + a1) + (a2 + a3);
    *reinterpret_cast<f32x4*>(out + i) = s;
}

// ---------------------------------------------------------------------------
extern "C" void kernel_launch(void* const* d_in, const int* in_sizes, int n_in,
                              void* d_out, int out_size, void* d_ws, size_t ws_size,
                              hipStream_t stream) {
    const float* dec = (const float*)d_in[0];
    const float* emb = (const float*)d_in[1];
    const int* emask = (const int*)d_in[2];
    const float* W = (const float*)d_in[3];
    const float* bias = (const float*)d_in[4];

    float* out = (float*)d_out;
    float* attn = out + (size_t)NB * TQn * DOUTn;  // 2,097,152 floats of `out` first

    char* wsb = (char*)d_ws;
    u16* ds_hi = (u16*)wsb;
    wsb += (size_t)NB * TQn * DOUTn * 2;
    u16* ds_lo = (u16*)wsb;
    wsb += (size_t)NB * TQn * DOUTn * 2;
    _Float16* embT = (_Float16*)wsb;
    wsb += (size_t)NB * DOUTn * TKn * 2;
    float* inv_sum = (float*)wsb;
    wsb += (size_t)NB * TQn * 4;
    float* partial = (float*)wsb;  // 4 * 8192 * 256 fp32 = 33.5 MB

    k_embT<<<dim3(TKn / 64, DOUTn / 64, NB), 256, 0, stream>>>(emb, embT);
    k_linear<<<dim3((NB * TQn) / 128, DOUTn / 64), 256, 0, stream>>>(dec, W, bias, ds_hi, ds_lo);
    k_scores<<<dim3(TQn / 128, TKn / 128, NB), 256, 0, stream>>>(ds_hi, ds_lo, emb, emask, attn);
    k_stats<<<dim3((NB * TQn) / 16), 256, 0, stream>>>(attn, inv_sum);
    k_pv<<<dim3(TQn / 64, 4, NB), 256, 0, stream>>>(attn, embT, inv_sum, partial);
    k_reduce<<<dim3(((size_t)NB * TQn * DOUTn / 4) / 256), 256, 0, stream>>>(partial, out);
}

// Round 3
// 209.789 us; speedup vs baseline: 1.7016x; 1.7016x over previous
//
#include <hip/hip_runtime.h>
#include <hip/hip_bf16.h>
#include <hip/hip_fp16.h>

typedef unsigned short u16;
typedef __attribute__((ext_vector_type(8))) short short8;
typedef __attribute__((ext_vector_type(8))) u16 u16x8;
typedef __attribute__((ext_vector_type(4))) u16 u16x4;
typedef __attribute__((ext_vector_type(8))) _Float16 half8;
typedef __attribute__((ext_vector_type(4))) float f32x4;

#define NB 8
#define TQn 1024
#define TKn 4096
#define DINn 1024
#define DOUTn 256
#define NROWS (NB * TQn)
#define NKB (TKn / 128)
#define EXPSHIFT 40.0f

#define DEV static __device__ __forceinline__

DEV u16 f2bf(float x) {
    __hip_bfloat16 h = __float2bfloat16(x);
    return *reinterpret_cast<u16*>(&h);
}
DEV float bf2f(u16 u) {
    __hip_bfloat16 h;
    *reinterpret_cast<u16*>(&h) = u;
    return __bfloat162float(h);
}
DEV void split2(float x, u16& hi, u16& lo) {
    u16 h = f2bf(x);
    float hf = bf2f(h);
    hi = h;
    lo = f2bf(x - hf);
}
DEV void split4(const float4 v, u16x4& h, u16x4& l) {
    u16 h0, l0, h1, l1, h2, l2, h3, l3;
    split2(v.x, h0, l0);
    split2(v.y, h1, l1);
    split2(v.z, h2, l2);
    split2(v.w, h3, l3);
    h = (u16x4){h0, h1, h2, h3};
    l = (u16x4){l0, l1, l2, l3};
}

// ---------------------------------------------------------------------------
// Kernel 1: transpose+convert emb [B][TK][DOUT] fp32 -> embT [B][DOUT][TK] fp16
// ---------------------------------------------------------------------------
__global__ __launch_bounds__(256) void k_embT(const float* __restrict__ emb,
                                              _Float16* __restrict__ embT) {
    __shared__ float tile[64][65];
    const int b = blockIdx.z;
    const int k0 = blockIdx.x * 64;
    const int o0 = blockIdx.y * 64;
    const int t = threadIdx.x;
    const int c = t & 63;
    const int r0 = t >> 6;
#pragma unroll
    for (int i = 0; i < 16; i++) {
        int r = r0 + i * 4;  // k-local
        tile[c][r] = emb[((size_t)b * TKn + k0 + r) * DOUTn + o0 + c];
    }
    __syncthreads();
#pragma unroll
    for (int i = 0; i < 16; i++) {
        int r = r0 + i * 4;  // o-local
        embT[((size_t)b * DOUTn + o0 + r) * TKn + k0 + c] = (_Float16)tile[r][c];
    }
}

// ---------------------------------------------------------------------------
// Kernel 2: linear  decsmall = dec @ W^T + b, split into hi/lo bf16
// BM=128, BN=64, BK=32, 256 threads (4 waves, 2x2)
// ---------------------------------------------------------------------------
__global__ __launch_bounds__(256) void k_linear(const float* __restrict__ dec,
                                                const float* __restrict__ W,
                                                const float* __restrict__ bias,
                                                u16* __restrict__ ds_hi,
                                                u16* __restrict__ ds_lo) {
    __shared__ u16 sAh[128][40], sAl[128][40], sBh[64][40], sBl[64][40];
    const int t = threadIdx.x;
    const int m0 = blockIdx.x * 128;
    const int n0 = blockIdx.y * 64;
    const int w = t >> 6, lane = t & 63;
    const int wr = w >> 1, wc = w & 1;
    const int lr = lane & 15, kg8 = (lane >> 4) * 8;

    f32x4 acc[4][2];
#pragma unroll
    for (int m = 0; m < 4; m++)
#pragma unroll
        for (int n = 0; n < 2; n++) acc[m][n] = (f32x4){0.f, 0.f, 0.f, 0.f};

    for (int k0 = 0; k0 < DINn; k0 += 32) {
        __syncthreads();
#pragma unroll
        for (int i = 0; i < 4; i++) {
            int f = i * 256 + t;
            int row = f >> 3, c4 = (f & 7) * 4;
            const float4 v = *reinterpret_cast<const float4*>(
                dec + (size_t)(m0 + row) * DINn + k0 + c4);
            u16x4 h, l;
            split4(v, h, l);
            *reinterpret_cast<u16x4*>(&sAh[row][c4]) = h;
            *reinterpret_cast<u16x4*>(&sAl[row][c4]) = l;
        }
#pragma unroll
        for (int i = 0; i < 2; i++) {
            int f = i * 256 + t;
            int row = f >> 3, c4 = (f & 7) * 4;
            const float4 v = *reinterpret_cast<const float4*>(
                W + (size_t)(n0 + row) * DINn + k0 + c4);
            u16x4 h, l;
            split4(v, h, l);
            *reinterpret_cast<u16x4*>(&sBh[row][c4]) = h;
            *reinterpret_cast<u16x4*>(&sBl[row][c4]) = l;
        }
        __syncthreads();
        short8 ah[4], al[4], bh[2], bl[2];
#pragma unroll
        for (int m = 0; m < 4; m++) {
            int row = wr * 64 + m * 16 + lr;
            ah[m] = *reinterpret_cast<const short8*>(&sAh[row][kg8]);
            al[m] = *reinterpret_cast<const short8*>(&sAl[row][kg8]);
        }
#pragma unroll
        for (int n = 0; n < 2; n++) {
            int row = wc * 32 + n * 16 + lr;
            bh[n] = *reinterpret_cast<const short8*>(&sBh[row][kg8]);
            bl[n] = *reinterpret_cast<const short8*>(&sBl[row][kg8]);
        }
#pragma unroll
        for (int m = 0; m < 4; m++)
#pragma unroll
            for (int n = 0; n < 2; n++) {
                acc[m][n] = __builtin_amdgcn_mfma_f32_16x16x32_bf16(ah[m], bh[n], acc[m][n], 0, 0, 0);
                acc[m][n] = __builtin_amdgcn_mfma_f32_16x16x32_bf16(ah[m], bl[n], acc[m][n], 0, 0, 0);
                acc[m][n] = __builtin_amdgcn_mfma_f32_16x16x32_bf16(al[m], bh[n], acc[m][n], 0, 0, 0);
            }
    }
#pragma unroll
    for (int m = 0; m < 4; m++) {
#pragma unroll
        for (int n = 0; n < 2; n++) {
            int colg = n0 + wc * 32 + n * 16 + lr;
            float bv = bias[colg];
#pragma unroll
            for (int r = 0; r < 4; r++) {
                int rowg = m0 + wr * 64 + m * 16 + (lane >> 4) * 4 + r;
                float v = acc[m][n][r] + bv;
                u16 h, l;
                split2(v, h, l);
                ds_hi[(size_t)rowg * DOUTn + colg] = h;
                ds_lo[(size_t)rowg * DOUTn + colg] = l;
            }
        }
    }
}

// ---------------------------------------------------------------------------
// Kernel 3: scores GEMM (split 3-MFMA) + mask + p_u = exp(s - 40) write
//           + per-row partial sums -> partsum[kb][row]
// BM=128, BN=128, BK=32, 256 threads (4 waves, 2x2), K=DOUT=256
// ---------------------------------------------------------------------------
__global__ __launch_bounds__(256) void k_scores_exp(const u16* __restrict__ ds_hi,
                                                    const u16* __restrict__ ds_lo,
                                                    const float* __restrict__ emb,
                                                    const int* __restrict__ emask,
                                                    float* __restrict__ attn,
                                                    float* __restrict__ partsum) {
    __shared__ u16 sAh[128][40], sAl[128][40], sBh[128][40], sBl[128][40];
    __shared__ float sSum[2][128];
    const int t = threadIdx.x;
    const int q0 = blockIdx.x * 128;
    const int kb = blockIdx.y;
    const int kb0 = kb * 128;
    const int b = blockIdx.z;
    const int w = t >> 6, lane = t & 63;
    const int wr = w >> 1, wc = w & 1;
    const int lr = lane & 15, g = lane >> 4, kg8 = g * 8;

    f32x4 acc[4][4];
#pragma unroll
    for (int m = 0; m < 4; m++)
#pragma unroll
        for (int n = 0; n < 4; n++) acc[m][n] = (f32x4){0.f, 0.f, 0.f, 0.f};

    for (int o0 = 0; o0 < DOUTn; o0 += 32) {
        __syncthreads();
#pragma unroll
        for (int i = 0; i < 2; i++) {
            int f8 = i * 256 + t;
            int row = f8 >> 2, c8 = (f8 & 3) * 8;
            size_t src = (size_t)(b * TQn + q0 + row) * DOUTn + o0 + c8;
            *reinterpret_cast<u16x8*>(&sAh[row][c8]) =
                *reinterpret_cast<const u16x8*>(ds_hi + src);
            *reinterpret_cast<u16x8*>(&sAl[row][c8]) =
                *reinterpret_cast<const u16x8*>(ds_lo + src);
        }
#pragma unroll
        for (int i = 0; i < 4; i++) {
            int f = i * 256 + t;
            int row = f >> 3, c4 = (f & 7) * 4;
            const float4 v = *reinterpret_cast<const float4*>(
                emb + (size_t)(b * TKn + kb0 + row) * DOUTn + o0 + c4);
            u16x4 h, l;
            split4(v, h, l);
            *reinterpret_cast<u16x4*>(&sBh[row][c4]) = h;
            *reinterpret_cast<u16x4*>(&sBl[row][c4]) = l;
        }
        __syncthreads();
        short8 ah[4], al[4], bh[4], bl[4];
#pragma unroll
        for (int m = 0; m < 4; m++) {
            int row = wr * 64 + m * 16 + lr;
            ah[m] = *reinterpret_cast<const short8*>(&sAh[row][kg8]);
            al[m] = *reinterpret_cast<const short8*>(&sAl[row][kg8]);
        }
#pragma unroll
        for (int n = 0; n < 4; n++) {
            int row = wc * 64 + n * 16 + lr;
            bh[n] = *reinterpret_cast<const short8*>(&sBh[row][kg8]);
            bl[n] = *reinterpret_cast<const short8*>(&sBl[row][kg8]);
        }
#pragma unroll
        for (int m = 0; m < 4; m++)
#pragma unroll
            for (int n = 0; n < 4; n++) {
                acc[m][n] = __builtin_amdgcn_mfma_f32_16x16x32_bf16(ah[m], bh[n], acc[m][n], 0, 0, 0);
                acc[m][n] = __builtin_amdgcn_mfma_f32_16x16x32_bf16(ah[m], bl[n], acc[m][n], 0, 0, 0);
                acc[m][n] = __builtin_amdgcn_mfma_f32_16x16x32_bf16(al[m], bh[n], acc[m][n], 0, 0, 0);
            }
    }
    // epilogue: mask + exp(s - EXPSHIFT) + write p_u + per-row sums
    const int* em = emask + (size_t)b * TKn;
    float* pout = attn + ((size_t)(b * TQn + q0)) * TKn + kb0;
    float rowAcc[4][4];
#pragma unroll
    for (int m = 0; m < 4; m++)
#pragma unroll
        for (int r = 0; r < 4; r++) rowAcc[m][r] = 0.f;

#pragma unroll
    for (int n = 0; n < 4; n++) {
        int colL = wc * 64 + n * 16 + lr;
        int mk = em[kb0 + colL];
#pragma unroll
        for (int m = 0; m < 4; m++) {
#pragma unroll
            for (int r = 0; r < 4; r++) {
                int rowL = wr * 64 + m * 16 + g * 4 + r;
                float p = mk ? __expf(acc[m][n][r] - EXPSHIFT) : 0.f;
                pout[(size_t)rowL * TKn + colL] = p;
                rowAcc[m][r] += p;
            }
        }
    }
    // reduce across the 16 lanes (lr) of each quarter-group
#pragma unroll
    for (int m = 0; m < 4; m++) {
#pragma unroll
        for (int r = 0; r < 4; r++) {
            float v = rowAcc[m][r];
            v += __shfl_xor(v, 1);
            v += __shfl_xor(v, 2);
            v += __shfl_xor(v, 4);
            v += __shfl_xor(v, 8);
            if (lr == 0) sSum[wc][wr * 64 + m * 16 + g * 4 + r] = v;
        }
    }
    __syncthreads();
    if (t < 128) {
        partsum[(size_t)kb * NROWS + (size_t)b * TQn + q0 + t] =
            sSum[0][t] + sSum[1][t];
    }
}

// ---------------------------------------------------------------------------
// Kernel 4: inv_sum[row] = 1 / sum_kb partsum[kb][row]
// ---------------------------------------------------------------------------
__global__ __launch_bounds__(256) void k_rowsum(const float* __restrict__ partsum,
                                                float* __restrict__ inv_sum) {
    int row = blockIdx.x * 256 + threadIdx.x;
    float s = 0.f;
#pragma unroll
    for (int kb = 0; kb < NKB; kb++) s += partsum[(size_t)kb * NROWS + row];
    inv_sum[row] = 1.0f / s;
}

// ---------------------------------------------------------------------------
// Kernel 5: PV GEMM. Block: 64 q-rows x 256 o, K-chunk 1024 (kc in 0..3).
// Stages A = p_u*inv (writes final attn back), B = embT; fp16 MFMA from LDS.
// 256 threads (4 waves, each wave: all 64 rows x 64 cols)
// ---------------------------------------------------------------------------
__global__ __launch_bounds__(256) void k_pv2(float* __restrict__ attn,
                                             const _Float16* __restrict__ embT,
                                             const float* __restrict__ inv_sum,
                                             float* __restrict__ partial) {
    __shared__ u16 sA[64][40];   // fp16 bits, 64 rows x 32 k
    __shared__ u16 sB[256][40];  // fp16 bits, 256 o x 32 k
    const int t = threadIdx.x;
    const int w = t >> 6, lane = t & 63;
    const int lr = lane & 15, g = lane >> 4, kg8 = g * 8;
    const int q0 = blockIdx.x * 64;
    const int kc = blockIdx.y;
    const int b = blockIdx.z;
    const int kbase = kc * 1024;

    f32x4 acc[4][4];
#pragma unroll
    for (int m = 0; m < 4; m++)
#pragma unroll
        for (int n = 0; n < 4; n++) acc[m][n] = (f32x4){0.f, 0.f, 0.f, 0.f};

    for (int ks = 0; ks < 1024; ks += 32) {
        __syncthreads();
        // stage A: 64 rows x 32 k fp32 from attn (p_u), scale, write back, cvt
#pragma unroll
        for (int i = 0; i < 2; i++) {
            int f = i * 256 + t;
            int row = f >> 3, c4 = (f & 7) * 4;
            size_t gaddr = ((size_t)(b * TQn + q0 + row)) * TKn + kbase + ks + c4;
            f32x4 v = *reinterpret_cast<const f32x4*>(attn + gaddr);
            float inv = inv_sum[(size_t)b * TQn + q0 + row];
            v = v * inv;
            *reinterpret_cast<f32x4*>(attn + gaddr) = v;  // final attn
            u16x4 hv;
            hv[0] = __builtin_bit_cast(u16, (_Float16)v[0]);
            hv[1] = __builtin_bit_cast(u16, (_Float16)v[1]);
            hv[2] = __builtin_bit_cast(u16, (_Float16)v[2]);
            hv[3] = __builtin_bit_cast(u16, (_Float16)v[3]);
            *reinterpret_cast<u16x4*>(&sA[row][c4]) = hv;
        }
        // stage B: 256 o x 32 k fp16 from embT
#pragma unroll
        for (int i = 0; i < 4; i++) {
            int f = i * 256 + t;
            int row = f >> 2, c8 = (f & 3) * 8;
            *reinterpret_cast<u16x8*>(&sB[row][c8]) = *reinterpret_cast<const u16x8*>(
                embT + ((size_t)(b * DOUTn + row)) * TKn + kbase + ks + c8);
        }
        __syncthreads();
        half8 a[4], bb[4];
#pragma unroll
        for (int m = 0; m < 4; m++)
            a[m] = *reinterpret_cast<const half8*>(&sA[m * 16 + lr][kg8]);
#pragma unroll
        for (int n = 0; n < 4; n++)
            bb[n] = *reinterpret_cast<const half8*>(&sB[w * 64 + n * 16 + lr][kg8]);
#pragma unroll
        for (int m = 0; m < 4; m++)
#pragma unroll
            for (int n = 0; n < 4; n++)
                acc[m][n] = __builtin_amdgcn_mfma_f32_16x16x32_f16(a[m], bb[n], acc[m][n], 0, 0, 0);
    }
    // epilogue: partial[kc][row][col]
#pragma unroll
    for (int m = 0; m < 4; m++) {
#pragma unroll
        for (int n = 0; n < 4; n++) {
            int col = w * 64 + n * 16 + lr;
#pragma unroll
            for (int r = 0; r < 4; r++) {
                size_t grow = (size_t)b * TQn + q0 + m * 16 + g * 4 + r;
                partial[((size_t)kc * NROWS + grow) * DOUTn + col] = acc[m][n][r];
            }
        }
    }
}

// ---------------------------------------------------------------------------
// Kernel 6: out = sum of 4 partials
// ---------------------------------------------------------------------------
__global__ __launch_bounds__(256) void k_reduce(const float* __restrict__ partial,
                                                float* __restrict__ out) {
    const size_t stride = (size_t)NROWS * DOUTn;
    size_t i = ((size_t)blockIdx.x * 256 + threadIdx.x) * 4;
    f32x4 a0 = *reinterpret_cast<const f32x4*>(partial + i);
    f32x4 a1 = *reinterpret_cast<const f32x4*>(partial + stride + i);
    f32x4 a2 = *reinterpret_cast<const f32x4*>(partial + 2 * stride + i);
    f32x4 a3 = *reinterpret_cast<const f32x4*>(partial + 3 * stride + i);
    f32x4 s = (a0 + a1) + (a2 + a3);
    *reinterpret_cast<f32x4*>(out + i) = s;
}

// ---------------------------------------------------------------------------
extern "C" void kernel_launch(void* const* d_in, const int* in_sizes, int n_in,
                              void* d_out, int out_size, void* d_ws, size_t ws_size,
                              hipStream_t stream) {
    const float* dec = (const float*)d_in[0];
    const float* emb = (const float*)d_in[1];
    const int* emask = (const int*)d_in[2];
    const float* W = (const float*)d_in[3];
    const float* bias = (const float*)d_in[4];

    float* out = (float*)d_out;
    float* attn = out + (size_t)NROWS * DOUTn;

    char* wsb = (char*)d_ws;
    u16* ds_hi = (u16*)wsb;
    wsb += (size_t)NROWS * DOUTn * 2;
    u16* ds_lo = (u16*)wsb;
    wsb += (size_t)NROWS * DOUTn * 2;
    _Float16* embT = (_Float16*)wsb;
    wsb += (size_t)NB * DOUTn * TKn * 2;
    float* inv_sum = (float*)wsb;
    wsb += (size_t)NROWS * 4;
    float* partial = (float*)wsb;  // 4 * 8192 * 256 fp32 = 33.5 MB
    // partsum (32 * 8192 fp32 = 1 MB) aliases the partial buffer: it is fully
    // consumed by k_rowsum before k_pv2 writes partial.
    float* partsum = partial;

    k_embT<<<dim3(TKn / 64, DOUTn / 64, NB), 256, 0, stream>>>(emb, embT);
    k_linear<<<dim3(NROWS / 128, DOUTn / 64), 256, 0, stream>>>(dec, W, bias, ds_hi, ds_lo);
    k_scores_exp<<<dim3(TQn / 128, NKB, NB), 256, 0, stream>>>(ds_hi, ds_lo, emb, emask, attn, partsum);
    k_rowsum<<<dim3(NROWS / 256), 256, 0, stream>>>(partsum, inv_sum);
    k_pv2<<<dim3(TQn / 64, 4, NB), 256, 0, stream>>>(attn, embT, inv_sum, partial);
    k_reduce<<<dim3((NROWS * DOUTn / 4) / 256), 256, 0, stream>>>(partial, out);
}